// Round 13
// baseline (192.306 us; speedup 1.0000x reference)
//
#include <hip/hip_runtime.h>

#define INF_DELTA 1e10f
#define LOG2E 1.4426950408889634f
#define LOG2_EPS -33.219280948873623f   // log2(1e-10)

// Native vector type for nontemporal builtins.
typedef float floatx4 __attribute__((ext_vector_type(4)));

// DPP helper: old=0, bound_ctrl=false -> out-of-range reads produce 0
// (additive identity). Row ops are confined to 16-lane rows.
template<int CTRL, int RMASK>
__device__ __forceinline__ float dpp0(float v) {
    return __int_as_float(
        __builtin_amdgcn_update_dpp(0, __float_as_int(v), CTRL, RMASK, 0xF, false));
}

__device__ __forceinline__ float log2_softplus(float x) {
    // log2(1+e^x) = relu(x)*log2e + log2(1 + exp2(-|x|*log2e))
    const float q  = __builtin_amdgcn_exp2f(-__builtin_fabsf(x) * LOG2E);
    const float l2 = __builtin_amdgcn_logf(1.0f + q);
    return __builtin_fmaf(__builtin_fmaxf(x, 0.0f), LOG2E, l2);
}

// Skewed LDS unit map: 16B unit u -> dword offset. One pad unit per 8 units
// breaks the mod-8 bank periodicity (write quads distinct, read quads balanced).
__device__ __forceinline__ int unit_off(int u) { return 4 * (u + (u >> 3)); }

// R10 (all-NT + contiguous color loads via LDS transpose — champion) with ONE
// variable changed: PERSISTENT grid-stride waves with next-tile register
// prefetch. Burst-then-die waves have bytes in flight only during their
// initial burst; a grid-stride wave that issues tile t+1's 5 NT loads before
// computing tile t keeps its ~5KB continuously in flight and eliminates the
// 131k-wave launch/drain churn. (Untested matrix cell: persistent x NT.
// R6's persistent-x-cached null was masked by the L3-path serializer.)
__global__ __launch_bounds__(256) void raymarch_kernel(
    const float* __restrict__ colors,      // (n_rays, 64, 3)
    const float* __restrict__ densities,   // (n_rays, 64)
    const float* __restrict__ depths,      // (n_rays, 64)
    float* __restrict__ rgb_out,           // (n_rays, 3)
    float* __restrict__ depth_out,         // (n_rays,)
    float* __restrict__ weights_out,       // (n_rays, 64)
    float* __restrict__ trans_out,         // (n_rays,)
    int n_rays)
{
    // 216 units * 4 floats per wave (192 data units + 24 skew-pad), 4 waves.
    __shared__ float lds[4][216 * 4];

    const int lane = threadIdx.x & 63;
    const int wid  = threadIdx.x >> 6;
    const int nblk = n_rays >> 2;                // 4-ray tiles
    const int nw   = gridDim.x * 4;              // total waves
    int t = blockIdx.x * 4 + wid;                // this wave's first tile
    if (t >= nblk) return;

    float* wbuf = lds[wid];                      // wave-private: no barriers

    // ---- prologue: NT-load tile t (5 contiguous dwordx4) ----
    long fb = (long)t * 256;
    const float* cb0 = colors + fb * 3;
    floatx4 ch0 = __builtin_nontemporal_load(
        reinterpret_cast<const floatx4*>(cb0 + (0 * 64 + lane) * 4));
    floatx4 ch1 = __builtin_nontemporal_load(
        reinterpret_cast<const floatx4*>(cb0 + (1 * 64 + lane) * 4));
    floatx4 ch2 = __builtin_nontemporal_load(
        reinterpret_cast<const floatx4*>(cb0 + (2 * 64 + lane) * 4));
    floatx4 d4 = __builtin_nontemporal_load(
        reinterpret_cast<const floatx4*>(depths    + fb + lane * 4));
    floatx4 x4 = __builtin_nontemporal_load(
        reinterpret_cast<const floatx4*>(densities + fb + lane * 4));

    while (true) {
        const int  tn   = t + nw;
        const bool more = (tn < nblk);

        // ---- prefetch tile t+nw BEFORE computing tile t ----
        floatx4 nch0, nch1, nch2, nd4, nx4;
        if (more) {
            const long fbn = (long)tn * 256;
            const float* cbn = colors + fbn * 3;
            nch0 = __builtin_nontemporal_load(
                reinterpret_cast<const floatx4*>(cbn + (0 * 64 + lane) * 4));
            nch1 = __builtin_nontemporal_load(
                reinterpret_cast<const floatx4*>(cbn + (1 * 64 + lane) * 4));
            nch2 = __builtin_nontemporal_load(
                reinterpret_cast<const floatx4*>(cbn + (2 * 64 + lane) * 4));
            nd4 = __builtin_nontemporal_load(
                reinterpret_cast<const floatx4*>(depths    + fbn + lane * 4));
            nx4 = __builtin_nontemporal_load(
                reinterpret_cast<const floatx4*>(densities + fbn + lane * 4));
        }

        // ---- compute tile t (R10 body verbatim) ----
        const long fbase = (long)t * 256;

        // transpose colors via skewed LDS (wave-private, conflict-free)
        *reinterpret_cast<floatx4*>(wbuf + unit_off(0 * 64 + lane)) = ch0;
        *reinterpret_cast<floatx4*>(wbuf + unit_off(1 * 64 + lane)) = ch1;
        *reinterpret_cast<floatx4*>(wbuf + unit_off(2 * 64 + lane)) = ch2;
        // lane l owns floats 12l..12l+11 = units 3l, 3l+1, 3l+2
        const floatx4 ca = *reinterpret_cast<const floatx4*>(wbuf + unit_off(3 * lane));
        const floatx4 cbv = *reinterpret_cast<const floatx4*>(wbuf + unit_off(3 * lane + 1));
        const floatx4 cc = *reinterpret_cast<const floatx4*>(wbuf + unit_off(3 * lane + 2));
        // samples: s0=(ca.x,ca.y,ca.z) s1=(ca.w,cbv.x,cbv.y)
        //          s2=(cbv.z,cbv.w,cc.x) s3=(cc.y,cc.z,cc.w)

        // deltas: seam value from next lane via DPP row_shl:1
        const float dnx  = dpp0<0x101, 0xF>(d4.x);
        const float del0 = d4.y - d4.x;
        const float del1 = d4.z - d4.y;
        const float del2 = d4.w - d4.z;
        const float del3 = ((lane & 15) == 15) ? INF_DELTA : (dnx - d4.w);

        // per-sample log2-domain alpha
        const float g0 = -del0 * log2_softplus(x4.x);
        const float g1 = -del1 * log2_softplus(x4.y);
        const float g2 = -del2 * log2_softplus(x4.z);
        const float g3 = -del3 * log2_softplus(x4.w);
        const float a0 = 1.0f - __builtin_amdgcn_exp2f(g0);
        const float a1 = 1.0f - __builtin_amdgcn_exp2f(g1);
        const float a2 = 1.0f - __builtin_amdgcn_exp2f(g2);
        const float a3 = 1.0f - __builtin_amdgcn_exp2f(g3);
        // log2(y + 1e-10) ~= max(g, log2(1e-10))
        const float l0 = __builtin_fmaxf(g0, LOG2_EPS);
        const float l1 = __builtin_fmaxf(g1, LOG2_EPS);
        const float l2 = __builtin_fmaxf(g2, LOG2_EPS);
        const float l3 = __builtin_fmaxf(g3, LOG2_EPS);

        // cumsum: serial-4 local + 4-step DPP scan across the 16-lane row
        const float L0 = l0;
        const float L1 = L0 + l1;
        const float L2 = L1 + l2;
        const float L3 = L2 + l3;
        float p = L3;
        p += dpp0<0x111, 0xF>(p);   // row_shr:1
        p += dpp0<0x112, 0xF>(p);   // row_shr:2
        p += dpp0<0x114, 0xF>(p);   // row_shr:4
        p += dpp0<0x118, 0xF>(p);   // row_shr:8
        const float excl = p - L3;  // exclusive lane prefix

        const float e0 = __builtin_amdgcn_exp2f(excl);
        const float e1 = __builtin_amdgcn_exp2f(excl + L0);
        const float e2 = __builtin_amdgcn_exp2f(excl + L1);
        const float e3 = __builtin_amdgcn_exp2f(excl + L2);

        const float w0 = a0 * e0;
        const float w1 = a1 * e1;
        const float w2 = a2 * e2;
        const float w3 = a3 * e3;

        // weights: one NON-TEMPORAL dwordx4 store
        floatx4 wv; wv.x = w0; wv.y = w1; wv.z = w2; wv.w = w3;
        __builtin_nontemporal_store(wv,
            reinterpret_cast<floatx4*>(weights_out + fbase + lane * 4));

        // per-ray reductions (r,g,b,depth) within each 16-lane row
        float p0 = w0 * ca.x  + w1 * ca.w  + w2 * cbv.z + w3 * cc.y;   // R
        float p1 = w0 * ca.y  + w1 * cbv.x + w2 * cbv.w + w3 * cc.z;   // G
        float p2 = w0 * ca.z  + w1 * cbv.y + w2 * cc.x  + w3 * cc.w;   // B
        float p3 = w0 * d4.x  + w1 * d4.y  + w2 * d4.z  + w3 * d4.w;   // depth

        p0 += dpp0<0xB1, 0xF>(p0);  // quad_perm [1,0,3,2]
        p1 += dpp0<0xB1, 0xF>(p1);
        p2 += dpp0<0xB1, 0xF>(p2);
        p3 += dpp0<0xB1, 0xF>(p3);
        p0 += dpp0<0x4E, 0xF>(p0);  // quad_perm [2,3,0,1] -> quad sums
        p1 += dpp0<0x4E, 0xF>(p1);
        p2 += dpp0<0x4E, 0xF>(p2);
        p3 += dpp0<0x4E, 0xF>(p3);

        const int c   = lane & 15;
        const int sel = lane & 3;
        float v = (sel == 0) ? p0 : (sel == 1) ? p1 : (sel == 2) ? p2 : p3;
        v += dpp0<0x124, 0xF>(v);   // row_ror:4 (preserves lane&3)
        v += dpp0<0x128, 0xF>(v);   // row_ror:8 -> row total of channel sel

        const int ray = t * 4 + (lane >> 4);
        if (c < 3) {
            __builtin_nontemporal_store(v, rgb_out + (long)ray * 3 + c);
        } else if (c == 3) {
            __builtin_nontemporal_store(v, depth_out + ray);
        }
        if (c == 15) {
            __builtin_nontemporal_store(__builtin_amdgcn_exp2f(p), trans_out + ray);
        }

        if (!more) break;
        // rotate prefetched registers in
        ch0 = nch0; ch1 = nch1; ch2 = nch2; d4 = nd4; x4 = nx4;
        t = tn;
    }
}

extern "C" void kernel_launch(void* const* d_in, const int* in_sizes, int n_in,
                              void* d_out, int out_size, void* d_ws, size_t ws_size,
                              hipStream_t stream) {
    const float* colors    = (const float*)d_in[0];
    const float* densities = (const float*)d_in[1];
    const float* depths    = (const float*)d_in[2];

    const int n_rays = in_sizes[1] / 64;   // densities flat count = n_rays * 64

    float* out      = (float*)d_out;
    float* rgb      = out;                              // n_rays*3
    float* depth_o  = rgb + (long)n_rays * 3;           // n_rays
    float* weights  = depth_o + n_rays;                 // n_rays*64
    float* trans    = weights + (long)n_rays * 64;      // n_rays

    const int nblk = n_rays / 4;                        // 4-ray tiles
    // Persistent grid: 1024 blocks (4 waves each -> 4096 waves, ~4 tiles/wave,
    // 16 waves/CU). Prefetch pipeline keeps each wave's loads in flight.
    int blocks = 1024;
    if (blocks > (nblk + 3) / 4) blocks = (nblk + 3) / 4;
    raymarch_kernel<<<blocks, 256, 0, stream>>>(
        colors, densities, depths, rgb, depth_o, weights, trans, n_rays);
}

// Round 14
// 189.798 us; speedup vs baseline: 1.0132x; 1.0132x over previous
//
#include <hip/hip_runtime.h>

#define INF_DELTA 1e10f
#define LOG2E 1.4426950408889634f
#define LOG2_EPS -33.219280948873623f   // log2(1e-10)

// Native vector type for nontemporal builtins.
typedef float floatx4 __attribute__((ext_vector_type(4)));

// DPP helper: old=0, bound_ctrl=false -> out-of-range reads produce 0
// (additive identity). Row ops are confined to 16-lane rows.
template<int CTRL, int RMASK>
__device__ __forceinline__ float dpp0(float v) {
    return __int_as_float(
        __builtin_amdgcn_update_dpp(0, __float_as_int(v), CTRL, RMASK, 0xF, false));
}

__device__ __forceinline__ float log2_softplus(float x) {
    // log2(1+e^x) = relu(x)*log2e + log2(1 + exp2(-|x|*log2e))
    const float q  = __builtin_amdgcn_exp2f(-__builtin_fabsf(x) * LOG2E);
    const float l2 = __builtin_amdgcn_logf(1.0f + q);
    return __builtin_fmaf(__builtin_fmaxf(x, 0.0f), LOG2E, l2);
}

// Skewed LDS unit map: 16B unit u -> dword offset. One pad unit per 8 units
// breaks the mod-8 bank periodicity (write quads distinct, read quads balanced).
__device__ __forceinline__ int unit_off(int u) { return 4 * (u + (u >> 3)); }

// CHAMPION (R10): all-NT cache bypass (loads AND stores — the L2/L3
// probe/allocate path was the serializer, +17% proven R7/R8) + perfectly
// contiguous color loads transposed through a wave-private skewed LDS buffer
// (+1.3%, R10). Wave64 owns 4 consecutive rays: 16-lane row per ray, lane
// owns 4 consecutive samples; every global access is a 16B/lane dwordx4.
// Probed-to-null: MLP depth (R2/R9/R13), lane-address rate (R3), cached
// variants (R5/R11/R12), persistent waves (R6/R13), DPP vs LDS pipes (R1).
__global__ __launch_bounds__(256) void raymarch_kernel(
    const float* __restrict__ colors,      // (n_rays, 64, 3)
    const float* __restrict__ densities,   // (n_rays, 64)
    const float* __restrict__ depths,      // (n_rays, 64)
    float* __restrict__ rgb_out,           // (n_rays, 3)
    float* __restrict__ depth_out,         // (n_rays,)
    float* __restrict__ weights_out,       // (n_rays, 64)
    float* __restrict__ trans_out,         // (n_rays,)
    int n_rays)
{
    // 216 units * 4 floats per wave (192 data units + 24 skew-pad), 4 waves.
    __shared__ float lds[4][216 * 4];

    const int lane = threadIdx.x & 63;
    const int wid  = threadIdx.x >> 6;
    const int blk  = blockIdx.x * 4 + wid;       // 4-ray block index
    const int nblk = n_rays >> 2;
    if (blk >= nblk) return;

    float* wbuf = lds[wid];                      // wave-private: no barriers
    const long fbase = (long)blk * 256;          // first flat sample of block

    // ---- 5 x NON-TEMPORAL dwordx4, ALL perfectly contiguous per instr ----
    const float* cbase = colors + fbase * 3;     // 3072B color block
    const floatx4 ch0 = __builtin_nontemporal_load(
        reinterpret_cast<const floatx4*>(cbase + (0 * 64 + lane) * 4));
    const floatx4 ch1 = __builtin_nontemporal_load(
        reinterpret_cast<const floatx4*>(cbase + (1 * 64 + lane) * 4));
    const floatx4 ch2 = __builtin_nontemporal_load(
        reinterpret_cast<const floatx4*>(cbase + (2 * 64 + lane) * 4));
    const floatx4 d4 = __builtin_nontemporal_load(
        reinterpret_cast<const floatx4*>(depths    + fbase + lane * 4));
    const floatx4 x4 = __builtin_nontemporal_load(
        reinterpret_cast<const floatx4*>(densities + fbase + lane * 4));

    // ---- transpose colors via skewed LDS (wave-private, conflict-free) ----
    *reinterpret_cast<floatx4*>(wbuf + unit_off(0 * 64 + lane)) = ch0;
    *reinterpret_cast<floatx4*>(wbuf + unit_off(1 * 64 + lane)) = ch1;
    *reinterpret_cast<floatx4*>(wbuf + unit_off(2 * 64 + lane)) = ch2;
    // lane l owns floats 12l..12l+11 = units 3l, 3l+1, 3l+2
    const floatx4 ca = *reinterpret_cast<const floatx4*>(wbuf + unit_off(3 * lane));
    const floatx4 cb = *reinterpret_cast<const floatx4*>(wbuf + unit_off(3 * lane + 1));
    const floatx4 cc = *reinterpret_cast<const floatx4*>(wbuf + unit_off(3 * lane + 2));
    // lane's samples: s0..s3 ; colors: s0=(ca.x,ca.y,ca.z) s1=(ca.w,cb.x,cb.y)
    //                          s2=(cb.z,cb.w,cc.x) s3=(cc.y,cc.z,cc.w)

    // ---- deltas: seam value from next lane via DPP row_shl:1 ----
    const float dnx  = dpp0<0x101, 0xF>(d4.x);   // lane l <- lane l+1's s0
    const float del0 = d4.y - d4.x;
    const float del1 = d4.z - d4.y;
    const float del2 = d4.w - d4.z;
    const float del3 = ((lane & 15) == 15) ? INF_DELTA : (dnx - d4.w);

    // ---- per-sample log2-domain alpha ----
    const float g0 = -del0 * log2_softplus(x4.x);
    const float g1 = -del1 * log2_softplus(x4.y);
    const float g2 = -del2 * log2_softplus(x4.z);
    const float g3 = -del3 * log2_softplus(x4.w);
    const float a0 = 1.0f - __builtin_amdgcn_exp2f(g0);
    const float a1 = 1.0f - __builtin_amdgcn_exp2f(g1);
    const float a2 = 1.0f - __builtin_amdgcn_exp2f(g2);
    const float a3 = 1.0f - __builtin_amdgcn_exp2f(g3);
    // log2(y + 1e-10) ~= max(g, log2(1e-10))
    const float l0 = __builtin_fmaxf(g0, LOG2_EPS);
    const float l1 = __builtin_fmaxf(g1, LOG2_EPS);
    const float l2 = __builtin_fmaxf(g2, LOG2_EPS);
    const float l3 = __builtin_fmaxf(g3, LOG2_EPS);

    // ---- cumsum: serial-4 local + 4-step DPP scan across the 16-lane row ----
    const float L0 = l0;
    const float L1 = L0 + l1;
    const float L2 = L1 + l2;
    const float L3 = L2 + l3;
    float p = L3;
    p += dpp0<0x111, 0xF>(p);   // row_shr:1
    p += dpp0<0x112, 0xF>(p);   // row_shr:2
    p += dpp0<0x114, 0xF>(p);   // row_shr:4
    p += dpp0<0x118, 0xF>(p);   // row_shr:8  (row-confined: full 16-lane scan)
    const float excl = p - L3;  // exclusive lane prefix

    // trans_excl per sample = exp2(excl + L_{j-1})
    const float e0 = __builtin_amdgcn_exp2f(excl);
    const float e1 = __builtin_amdgcn_exp2f(excl + L0);
    const float e2 = __builtin_amdgcn_exp2f(excl + L1);
    const float e3 = __builtin_amdgcn_exp2f(excl + L2);

    const float w0 = a0 * e0;
    const float w1 = a1 * e1;
    const float w2 = a2 * e2;
    const float w3 = a3 * e3;

    // ---- weights: one NON-TEMPORAL dwordx4 store ----
    floatx4 wv; wv.x = w0; wv.y = w1; wv.z = w2; wv.w = w3;
    __builtin_nontemporal_store(wv,
        reinterpret_cast<floatx4*>(weights_out + fbase + lane * 4));

    // ---- per-ray reductions (r,g,b,depth) within each 16-lane row ----
    float p0 = w0 * ca.x + w1 * ca.w + w2 * cb.z + w3 * cc.y;   // R
    float p1 = w0 * ca.y + w1 * cb.x + w2 * cb.w + w3 * cc.z;   // G
    float p2 = w0 * ca.z + w1 * cb.y + w2 * cc.x + w3 * cc.w;   // B
    float p3 = w0 * d4.x + w1 * d4.y + w2 * d4.z + w3 * d4.w;   // depth

    p0 += dpp0<0xB1, 0xF>(p0);  // quad_perm [1,0,3,2]
    p1 += dpp0<0xB1, 0xF>(p1);
    p2 += dpp0<0xB1, 0xF>(p2);
    p3 += dpp0<0xB1, 0xF>(p3);
    p0 += dpp0<0x4E, 0xF>(p0);  // quad_perm [2,3,0,1] -> quad sums
    p1 += dpp0<0x4E, 0xF>(p1);
    p2 += dpp0<0x4E, 0xF>(p2);
    p3 += dpp0<0x4E, 0xF>(p3);

    const int c = lane & 15;
    const int sel = lane & 3;
    float v = (sel == 0) ? p0 : (sel == 1) ? p1 : (sel == 2) ? p2 : p3;
    v += dpp0<0x124, 0xF>(v);   // row_ror:4 (preserves lane&3)
    v += dpp0<0x128, 0xF>(v);   // row_ror:8 -> row total of channel sel

    const int ray = blk * 4 + (lane >> 4);
    if (c < 3) {
        __builtin_nontemporal_store(v, rgb_out + (long)ray * 3 + c);
    } else if (c == 3) {
        __builtin_nontemporal_store(v, depth_out + ray);
    }
    if (c == 15) {
        __builtin_nontemporal_store(__builtin_amdgcn_exp2f(p), trans_out + ray);
    }
}

extern "C" void kernel_launch(void* const* d_in, const int* in_sizes, int n_in,
                              void* d_out, int out_size, void* d_ws, size_t ws_size,
                              hipStream_t stream) {
    const float* colors    = (const float*)d_in[0];
    const float* densities = (const float*)d_in[1];
    const float* depths    = (const float*)d_in[2];

    const int n_rays = in_sizes[1] / 64;   // densities flat count = n_rays * 64

    float* out      = (float*)d_out;
    float* rgb      = out;                              // n_rays*3
    float* depth_o  = rgb + (long)n_rays * 3;           // n_rays
    float* weights  = depth_o + n_rays;                 // n_rays*64
    float* trans    = weights + (long)n_rays * 64;      // n_rays

    const int nblk   = n_rays / 4;                      // 4 rays per wave
    const int blocks = (nblk + 3) / 4;                  // 4 waves per block
    raymarch_kernel<<<blocks, 256, 0, stream>>>(
        colors, densities, depths, rgb, depth_o, weights, trans, n_rays);
}